// Round 1
// baseline (2969.593 us; speedup 1.0000x reference)
//
#include <hip/hip_runtime.h>

#define T_LEN 512
#define D_DIM 32
#define N_DIM 64
#define B_ALL 128
#define B_TILE 16

__device__ __forceinline__ float rcp_f(float x) {
#if __has_builtin(__builtin_amdgcn_rcpf)
    return __builtin_amdgcn_rcpf(x);
#else
    return 1.0f / x;
#endif
}
__device__ __forceinline__ float tanh_f(float x) {
    // tanh(x) = 1 - 2/(exp(2x)+1); saturates correctly for |x| large
    float e = __expf(2.0f * x);
    return 1.0f - 2.0f * rcp_f(e + 1.0f);
}
__device__ __forceinline__ float sig_f(float x) {
    return rcp_f(1.0f + __expf(-x));
}

// One block per (d, batch-tile of 16). 256 threads, 1 block/CU.
// Stage-1 role: gate g = tid>>6; within gate wave: 4-batch x 4-n register tile.
//   W[g][k][n0..n0+3] for all k kept in 256 VGPRs per thread.
// Stage-3 role: thread owns (b = tid>>4, n-quad = (tid&15)*4): c/h update,
//   online alpha accumulation, h write-back to LDS for next step.
__global__ __launch_bounds__(256, 1)
void imv_lstm_scan(const float* __restrict__ x,
                   const float* __restrict__ Uj, const float* __restrict__ Ui,
                   const float* __restrict__ Uf, const float* __restrict__ Uo,
                   const float* __restrict__ Wj, const float* __restrict__ Wi,
                   const float* __restrict__ Wf, const float* __restrict__ Wo,
                   const float* __restrict__ bj, const float* __restrict__ bi_,
                   const float* __restrict__ bf_, const float* __restrict__ bo,
                   const float* __restrict__ Fa, const float* __restrict__ Fab,
                   const float* __restrict__ Fbw, const float* __restrict__ Fbb,
                   const float* __restrict__ Pw, const float* __restrict__ Pb,
                   float* __restrict__ wmu, float* __restrict__ wbeta)
{
    __shared__ float sX[B_TILE][T_LEN];     // 32 KB: x[b_local][t] for this d
    __shared__ float sH[B_TILE][N_DIM];     //  4 KB: h[b][k]
    __shared__ float sG[4][B_TILE][N_DIM];  // 16 KB: gate pre-activations

    const int tid = threadIdx.x;
    const int d   = blockIdx.x & 31;        // consecutive blocks share x cachelines
    const int bt  = blockIdx.x >> 5;
    const int bg0 = bt * B_TILE;

    // stage-1 role
    const int g   = tid >> 6;
    const int r   = tid & 63;
    const int b0s = (r >> 4) * 4;
    const int n0s = (r & 15) * 4;
    // stage-3 role
    const int b3  = tid >> 4;
    const int n03 = (tid & 15) * 4;

    const float* Wsel = (g == 0) ? Wj : (g == 1) ? Wi : (g == 2) ? Wf : Wo;
    const float* Usel = (g == 0) ? Uj : (g == 1) ? Ui : (g == 2) ? Uf : Uo;
    const float* Bsel = (g == 0) ? bj : (g == 1) ? bi_ : (g == 2) ? bf_ : bo;

    // W slice into registers: W[g][d][k][n0s..n0s+3] for k = 0..63
    float wreg[256];
    {
        const float* Wg = Wsel + d * (N_DIM * N_DIM) + n0s;
        #pragma unroll
        for (int k = 0; k < 64; ++k) {
            float4 w = *(const float4*)(Wg + k * N_DIM);
            wreg[k * 4 + 0] = w.x; wreg[k * 4 + 1] = w.y;
            wreg[k * 4 + 2] = w.z; wreg[k * 4 + 3] = w.w;
        }
    }
    float4 uv = *(const float4*)(Usel + d * N_DIM + n0s);
    float4 bv = *(const float4*)(Bsel + d * N_DIM + n0s);
    float ur[4] = {uv.x, uv.y, uv.z, uv.w};
    float br[4] = {bv.x, bv.y, bv.z, bv.w};

    float4 fav = *(const float4*)(Fa + d * N_DIM + n03);
    float far4[4] = {fav.x, fav.y, fav.z, fav.w};
    const float fab = Fab[d];

    // stage x[b, :, d] for this block's batch tile into LDS (one-time)
    for (int i = tid; i < B_TILE * T_LEN; i += 256) {
        int b = i >> 9, tt = i & (T_LEN - 1);
        sX[b][tt] = x[((size_t)(bg0 + b) * T_LEN + tt) * D_DIM + d];
    }
    ((float4*)sH)[tid] = make_float4(0.f, 0.f, 0.f, 0.f);  // h0 = 0
    __syncthreads();

    float c4[4]   = {0.f, 0.f, 0.f, 0.f};
    float h4[4]   = {0.f, 0.f, 0.f, 0.f};
    float gacc[4] = {0.f, 0.f, 0.f, 0.f};
    float asum    = 0.f;

    #pragma unroll 1
    for (int t = 0; t < T_LEN; ++t) {
        // ---------- stage 1: gate matmul (W in regs, h broadcast from LDS) ----------
        float acc[16];
        #pragma unroll
        for (int bi = 0; bi < 4; ++bi) {
            float xv = sX[b0s + bi][t];
            #pragma unroll
            for (int ni = 0; ni < 4; ++ni)
                acc[bi * 4 + ni] = fmaf(xv, ur[ni], br[ni]);
        }
        #pragma unroll
        for (int k4 = 0; k4 < 16; ++k4) {
            float hvv[16];
            #pragma unroll
            for (int bi = 0; bi < 4; ++bi) {
                float4 hv = *(const float4*)&sH[b0s + bi][k4 * 4];
                hvv[bi * 4 + 0] = hv.x; hvv[bi * 4 + 1] = hv.y;
                hvv[bi * 4 + 2] = hv.z; hvv[bi * 4 + 3] = hv.w;
            }
            #pragma unroll
            for (int kk = 0; kk < 4; ++kk) {
                #pragma unroll
                for (int bi = 0; bi < 4; ++bi) {
                    float hk = hvv[bi * 4 + kk];
                    #pragma unroll
                    for (int ni = 0; ni < 4; ++ni)
                        acc[bi * 4 + ni] =
                            fmaf(hk, wreg[(k4 * 4 + kk) * 4 + ni], acc[bi * 4 + ni]);
                }
            }
        }
        #pragma unroll
        for (int bi = 0; bi < 4; ++bi) {
            *(float4*)&sG[g][b0s + bi][n0s] =
                make_float4(acc[bi * 4 + 0], acc[bi * 4 + 1],
                            acc[bi * 4 + 2], acc[bi * 4 + 3]);
        }
        __syncthreads();

        // ---------- stage 3: nonlinearities, state update, online alpha ----------
        float4 jv = *(const float4*)&sG[0][b3][n03];
        float4 iv = *(const float4*)&sG[1][b3][n03];
        float4 fv = *(const float4*)&sG[2][b3][n03];
        float4 ov = *(const float4*)&sG[3][b3][n03];
        float jj[4] = {jv.x, jv.y, jv.z, jv.w};
        float ii[4] = {iv.x, iv.y, iv.z, iv.w};
        float ff[4] = {fv.x, fv.y, fv.z, fv.w};
        float oo[4] = {ov.x, ov.y, ov.z, ov.w};

        float ps = 0.f;
        #pragma unroll
        for (int i2 = 0; i2 < 4; ++i2) {
            float jt = tanh_f(jj[i2]);
            float it = sig_f(ii[i2]);
            float ft = sig_f(ff[i2]);
            float ot = sig_f(oo[i2]);
            c4[i2] = fmaf(c4[i2], ft, it * jt);
            h4[i2] = ot * tanh_f(c4[i2]);
            ps = fmaf(h4[i2], far4[i2], ps);
        }
        // reduce alpha-dot over the 16 lanes covering this b
        #pragma unroll
        for (int m = 1; m < 16; m <<= 1)
            ps += __shfl_xor(ps, m, 16);
        float al = __expf(tanh_f(ps + fab));
        asum += al;
        #pragma unroll
        for (int i2 = 0; i2 < 4; ++i2)
            gacc[i2] = fmaf(al, h4[i2], gacc[i2]);

        *(float4*)&sH[b3][n03] = make_float4(h4[0], h4[1], h4[2], h4[3]);
        __syncthreads();
    }

    // ---------- epilogue: g_n, mu, beta per (b, d) ----------
    float rs = 1.0f / asum;
    float4 pw0 = *(const float4*)(Pw + n03);
    float4 pw1 = *(const float4*)(Pw + 64 + n03);
    float4 fw0 = *(const float4*)(Fbw + n03);
    float4 fw1 = *(const float4*)(Fbw + 64 + n03);
    float pwa[4] = {pw0.x, pw0.y, pw0.z, pw0.w};
    float pwb[4] = {pw1.x, pw1.y, pw1.z, pw1.w};
    float fwa[4] = {fw0.x, fw0.y, fw0.z, fw0.w};
    float fwb[4] = {fw1.x, fw1.y, fw1.z, fw1.w};

    float pm = 0.f, pbv = 0.f;
    #pragma unroll
    for (int i2 = 0; i2 < 4; ++i2) {
        float gn = gacc[i2] * rs;
        pm  = fmaf(gn, pwa[i2], fmaf(h4[i2], pwb[i2], pm));
        pbv = fmaf(gn, fwa[i2], fmaf(h4[i2], fwb[i2], pbv));
    }
    #pragma unroll
    for (int m = 1; m < 16; m <<= 1) {
        pm  += __shfl_xor(pm, m, 16);
        pbv += __shfl_xor(pbv, m, 16);
    }
    if ((tid & 15) == 0) {
        float mu = pm + Pb[0];
        float be = __expf(tanh_f(pbv + Fbb[0]));
        int bglob = bg0 + b3;
        wmu[bglob * D_DIM + d]   = mu;
        wbeta[bglob * D_DIM + d] = be;
    }
}

// beta softmax over d + weighted sum -> out[b]
__global__ void imv_finalize(const float* __restrict__ wmu,
                             const float* __restrict__ wbeta,
                             float* __restrict__ out)
{
    int b = blockIdx.x * 64 + threadIdx.x;
    if (b >= B_ALL) return;
    float s1 = 0.f, s2 = 0.f;
    for (int d = 0; d < D_DIM; ++d) {
        float be = wbeta[b * D_DIM + d];
        s1 = fmaf(be, wmu[b * D_DIM + d], s1);
        s2 += be;
    }
    out[b] = s1 / s2;
}

extern "C" void kernel_launch(void* const* d_in, const int* in_sizes, int n_in,
                              void* d_out, int out_size, void* d_ws, size_t ws_size,
                              hipStream_t stream)
{
    const float* x   = (const float*)d_in[0];
    const float* U_j = (const float*)d_in[1];
    const float* U_i = (const float*)d_in[2];
    const float* U_f = (const float*)d_in[3];
    const float* U_o = (const float*)d_in[4];
    const float* W_j = (const float*)d_in[5];
    const float* W_i = (const float*)d_in[6];
    const float* W_f = (const float*)d_in[7];
    const float* W_o = (const float*)d_in[8];
    const float* b_j = (const float*)d_in[9];
    const float* b_i = (const float*)d_in[10];
    const float* b_f = (const float*)d_in[11];
    const float* b_o = (const float*)d_in[12];
    const float* Fan  = (const float*)d_in[13];
    const float* Fanb = (const float*)d_in[14];
    const float* Fbw  = (const float*)d_in[15];
    const float* Fbb  = (const float*)d_in[16];
    const float* Phw  = (const float*)d_in[17];
    const float* Phb  = (const float*)d_in[18];

    float* wmu   = (float*)d_ws;
    float* wbeta = wmu + B_ALL * D_DIM;

    imv_lstm_scan<<<dim3(256), dim3(256), 0, stream>>>(
        x, U_j, U_i, U_f, U_o, W_j, W_i, W_f, W_o,
        b_j, b_i, b_f, b_o, Fan, Fanb, Fbw, Fbb, Phw, Phb,
        wmu, wbeta);

    imv_finalize<<<dim3(2), dim3(64), 0, stream>>>(wmu, wbeta, (float*)d_out);
}

// Round 4
// 2002.609 us; speedup vs baseline: 1.4829x; 1.4829x over previous
//
#include <hip/hip_runtime.h>

#define T_LEN 512
#define D_DIM 32
#define N_DIM 64
#define B_ALL 128
#define B_TILE 8
#define SH_PAD 68   // row stride (floats) for sH/sG: 4b mod 32 spreads banks

__device__ __forceinline__ float rcp_f(float x) {
#if __has_builtin(__builtin_amdgcn_rcpf)
    return __builtin_amdgcn_rcpf(x);
#else
    return 1.0f / x;
#endif
}
__device__ __forceinline__ float tanh_f(float x) {
    float e = __expf(2.0f * x);
    return 1.0f - 2.0f * rcp_f(e + 1.0f);
}
__device__ __forceinline__ float sig_f(float x) {
    return rcp_f(1.0f + __expf(-x));
}

// Block = (d, 8-batch tile), 512 threads (8 waves), grid = 32*16 = 512.
// Stage-1 thread tile: gate g, b_width=2, n_width=8, k_width=16.
//   W slice = 16k x 8n = 128 VGPRs (fits: no spill).
//   Partial sums over k combined across 4 kg-lanes via shfl_xor(1|2).
//   NOTE: x*U + b seed must be counted ONCE -> only kg==0 lane seeds it.
// Stage-3 thread: one (b, n) element: gates, c/h update, online alpha.
__global__ __launch_bounds__(512, 2)
void imv_lstm_scan(const float* __restrict__ x,
                   const float* __restrict__ Uj, const float* __restrict__ Ui,
                   const float* __restrict__ Uf, const float* __restrict__ Uo,
                   const float* __restrict__ Wj, const float* __restrict__ Wi,
                   const float* __restrict__ Wf, const float* __restrict__ Wo,
                   const float* __restrict__ bj, const float* __restrict__ bi_,
                   const float* __restrict__ bf_, const float* __restrict__ bo,
                   const float* __restrict__ Fa, const float* __restrict__ Fab,
                   const float* __restrict__ Fbw, const float* __restrict__ Fbb,
                   const float* __restrict__ Pw, const float* __restrict__ Pb,
                   float* __restrict__ wmu, float* __restrict__ wbeta)
{
    __shared__ float sX[B_TILE][T_LEN];       // 16 KB
    __shared__ float sH[B_TILE][SH_PAD];      // 2.1 KB (padded)
    __shared__ float sG[4][B_TILE][SH_PAD];   // 8.5 KB (padded)

    const int tid = threadIdx.x;
    const int d   = blockIdx.x & 31;
    const int bt  = blockIdx.x >> 5;
    const int bg0 = bt * B_TILE;

    // ---- stage-1 role decode: idx = bg(2b) | no(3b) | kg(2b), per gate ----
    const int g   = tid >> 7;          // gate
    const int idx = tid & 127;
    const int kg  = idx & 3;           // k-group (16 k each) -> lane bits 0-1
    const int no  = (idx >> 2) & 7;    // n-octet
    const int bg  = idx >> 5;          // b-pair group (0..3) -> b = bg*2+bi
    const int n0  = no * 8;
    const int k0  = kg * 16;
    const float seed = (kg == 0) ? 1.0f : 0.0f;   // count x*U+b exactly once

    // ---- stage-3 role: one (b, n) element ----
    const int b3 = tid >> 6;           // 0..7 (one wave per b)
    const int n3 = tid & 63;

    const float* Wsel = (g == 0) ? Wj : (g == 1) ? Wi : (g == 2) ? Wf : Wo;
    const float* Usel = (g == 0) ? Uj : (g == 1) ? Ui : (g == 2) ? Uf : Uo;
    const float* Bsel = (g == 0) ? bj : (g == 1) ? bi_ : (g == 2) ? bf_ : bo;

    // W slice: W[g][d][k0+kl][n0..n0+7], kl = 0..15  -> 128 VGPRs
    float wreg[128];
    {
        const float* Wg = Wsel + d * (N_DIM * N_DIM);
        #pragma unroll
        for (int kl = 0; kl < 16; ++kl) {
            float4 wa = *(const float4*)(Wg + (k0 + kl) * N_DIM + n0);
            float4 wb = *(const float4*)(Wg + (k0 + kl) * N_DIM + n0 + 4);
            wreg[kl * 8 + 0] = wa.x; wreg[kl * 8 + 1] = wa.y;
            wreg[kl * 8 + 2] = wa.z; wreg[kl * 8 + 3] = wa.w;
            wreg[kl * 8 + 4] = wb.x; wreg[kl * 8 + 5] = wb.y;
            wreg[kl * 8 + 6] = wb.z; wreg[kl * 8 + 7] = wb.w;
        }
    }
    float u8[8], bb8[8];
    {
        float4 ua = *(const float4*)(Usel + d * N_DIM + n0);
        float4 ub = *(const float4*)(Usel + d * N_DIM + n0 + 4);
        float4 ba = *(const float4*)(Bsel + d * N_DIM + n0);
        float4 bbv = *(const float4*)(Bsel + d * N_DIM + n0 + 4);
        u8[0]=ua.x;u8[1]=ua.y;u8[2]=ua.z;u8[3]=ua.w;
        u8[4]=ub.x;u8[5]=ub.y;u8[6]=ub.z;u8[7]=ub.w;
        bb8[0]=ba.x;bb8[1]=ba.y;bb8[2]=ba.z;bb8[3]=ba.w;
        bb8[4]=bbv.x;bb8[5]=bbv.y;bb8[6]=bbv.z;bb8[7]=bbv.w;
    }
    const float far = Fa[d * N_DIM + n3];
    const float fab = Fab[d];

    // stage x[b, :, d] into LDS (one-time)
    for (int i = tid; i < B_TILE * T_LEN; i += 512) {
        int b = i >> 9, tt = i & (T_LEN - 1);
        sX[b][tt] = x[((size_t)(bg0 + b) * T_LEN + tt) * D_DIM + d];
    }
    // zero the FULL padded sH (544 floats > 512 threads — loop, not if)
    for (int i = tid; i < B_TILE * SH_PAD; i += 512)
        ((float*)sH)[i] = 0.f;
    __syncthreads();

    float cst  = 0.f, hst = 0.f;   // stage-3 state: c, h for (b3, n3)
    float gacc = 0.f, asum = 0.f;

    #pragma unroll 1
    for (int t = 0; t < T_LEN; ++t) {
        // ---------- stage 1: gate matmul, W in regs, h from LDS ----------
        float acc[16];   // [bi][ni] : 2 x 8
        #pragma unroll
        for (int bi = 0; bi < 2; ++bi) {
            float xv = sX[bg * 2 + bi][t] * seed;
            #pragma unroll
            for (int ni = 0; ni < 8; ++ni)
                acc[bi * 8 + ni] = fmaf(xv, u8[ni], bb8[ni] * seed);
        }
        #pragma unroll
        for (int k4 = 0; k4 < 4; ++k4) {
            float hv[8];  // [bi][kk]
            #pragma unroll
            for (int bi = 0; bi < 2; ++bi) {
                float4 h4 = *(const float4*)&sH[bg * 2 + bi][k0 + k4 * 4];
                hv[bi * 4 + 0] = h4.x; hv[bi * 4 + 1] = h4.y;
                hv[bi * 4 + 2] = h4.z; hv[bi * 4 + 3] = h4.w;
            }
            #pragma unroll
            for (int kk = 0; kk < 4; ++kk) {
                int kl = k4 * 4 + kk;
                #pragma unroll
                for (int bi = 0; bi < 2; ++bi) {
                    float hk = hv[bi * 4 + kk];
                    #pragma unroll
                    for (int ni = 0; ni < 8; ++ni)
                        acc[bi * 8 + ni] = fmaf(hk, wreg[kl * 8 + ni], acc[bi * 8 + ni]);
                }
            }
        }
        // combine k-partials across the 4 kg lanes (bits 0-1 of lane id)
        #pragma unroll
        for (int e = 0; e < 16; ++e) {
            acc[e] += __shfl_xor(acc[e], 1);
            acc[e] += __shfl_xor(acc[e], 2);
        }
        // each kg lane stores one quarter (float4) of the reduced 16
        {
            int bi_s = kg >> 1, half = kg & 1;
            float4 v = make_float4(acc[bi_s * 8 + half * 4 + 0],
                                   acc[bi_s * 8 + half * 4 + 1],
                                   acc[bi_s * 8 + half * 4 + 2],
                                   acc[bi_s * 8 + half * 4 + 3]);
            *(float4*)&sG[g][bg * 2 + bi_s][n0 + half * 4] = v;
        }
        __syncthreads();

        // ---------- stage 3: nonlinearities, state, online alpha ----------
        float jp = sG[0][b3][n3];
        float ip = sG[1][b3][n3];
        float fp = sG[2][b3][n3];
        float op = sG[3][b3][n3];
        float jt = tanh_f(jp);
        float it = sig_f(ip);
        float ft = sig_f(fp);
        float ot = sig_f(op);
        cst = fmaf(cst, ft, it * jt);
        hst = ot * tanh_f(cst);

        float ps = hst * far;
        #pragma unroll
        for (int m = 1; m < 64; m <<= 1)
            ps += __shfl_xor(ps, m);
        float al = __expf(tanh_f(ps + fab));
        asum += al;
        gacc = fmaf(al, hst, gacc);

        sH[b3][n3] = hst;
        __syncthreads();
    }

    // ---------- epilogue: per (b3, d) mu and beta ----------
    float gn  = gacc * (1.0f / asum);
    float pm  = fmaf(gn, Pw[n3],  hst * Pw[64 + n3]);
    float pbv = fmaf(gn, Fbw[n3], hst * Fbw[64 + n3]);
    #pragma unroll
    for (int m = 1; m < 64; m <<= 1) {
        pm  += __shfl_xor(pm, m);
        pbv += __shfl_xor(pbv, m);
    }
    if (n3 == 0) {
        int bglob = bg0 + b3;
        wmu[bglob * D_DIM + d]   = pm + Pb[0];
        wbeta[bglob * D_DIM + d] = __expf(tanh_f(pbv + Fbb[0]));
    }
}

// beta softmax over d + weighted sum -> out[b]
__global__ void imv_finalize(const float* __restrict__ wmu,
                             const float* __restrict__ wbeta,
                             float* __restrict__ out)
{
    int b = blockIdx.x * 64 + threadIdx.x;
    if (b >= B_ALL) return;
    float s1 = 0.f, s2 = 0.f;
    for (int d = 0; d < D_DIM; ++d) {
        float be = wbeta[b * D_DIM + d];
        s1 = fmaf(be, wmu[b * D_DIM + d], s1);
        s2 += be;
    }
    out[b] = s1 / s2;
}

extern "C" void kernel_launch(void* const* d_in, const int* in_sizes, int n_in,
                              void* d_out, int out_size, void* d_ws, size_t ws_size,
                              hipStream_t stream)
{
    const float* x   = (const float*)d_in[0];
    const float* U_j = (const float*)d_in[1];
    const float* U_i = (const float*)d_in[2];
    const float* U_f = (const float*)d_in[3];
    const float* U_o = (const float*)d_in[4];
    const float* W_j = (const float*)d_in[5];
    const float* W_i = (const float*)d_in[6];
    const float* W_f = (const float*)d_in[7];
    const float* W_o = (const float*)d_in[8];
    const float* b_j = (const float*)d_in[9];
    const float* b_i = (const float*)d_in[10];
    const float* b_f = (const float*)d_in[11];
    const float* b_o = (const float*)d_in[12];
    const float* Fan  = (const float*)d_in[13];
    const float* Fanb = (const float*)d_in[14];
    const float* Fbw  = (const float*)d_in[15];
    const float* Fbb  = (const float*)d_in[16];
    const float* Phw  = (const float*)d_in[17];
    const float* Phb  = (const float*)d_in[18];

    float* wmu   = (float*)d_ws;
    float* wbeta = wmu + B_ALL * D_DIM;

    imv_lstm_scan<<<dim3(512), dim3(512), 0, stream>>>(
        x, U_j, U_i, U_f, U_o, W_j, W_i, W_f, W_o,
        b_j, b_i, b_f, b_o, Fan, Fanb, Fbw, Fbb, Phw, Phb,
        wmu, wbeta);

    imv_finalize<<<dim3(2), dim3(64), 0, stream>>>(wmu, wbeta, (float*)d_out);
}

// Round 5
// 1825.167 us; speedup vs baseline: 1.6270x; 1.0972x over previous
//
#include <hip/hip_runtime.h>

#define T_LEN 512
#define D_DIM 32
#define N_DIM 64
#define B_ALL 128
#define B_TILE 4
#define SH_PAD 72   // row stride: 288 B (32B-aligned rows, +8 banks/row)

typedef float f8 __attribute__((ext_vector_type(8)));

__device__ __forceinline__ float rcp_f(float x) {
#if __has_builtin(__builtin_amdgcn_rcpf)
    return __builtin_amdgcn_rcpf(x);
#else
    return 1.0f / x;
#endif
}
__device__ __forceinline__ float tanh_f(float x) {
    float e = __expf(2.0f * x);
    return 1.0f - 2.0f * rcp_f(e + 1.0f);
}
__device__ __forceinline__ float sig_f(float x) {
    return rcp_f(1.0f + __expf(-x));
}
// LDS 32-byte read as two b128s with constant-index assembly (promotable)
__device__ __forceinline__ f8 ldsf8(const float* p) {
    float4 a = *(const float4*)p;
    float4 b = *(const float4*)(p + 4);
    f8 r;
    r[0]=a.x; r[1]=a.y; r[2]=a.z; r[3]=a.w;
    r[4]=b.x; r[5]=b.y; r[6]=b.z; r[7]=b.w;
    return r;
}

// Block = (d, 4-batch tile), 256 threads (4 waves), grid = 32*32 = 1024.
// 2 blocks/CU (waves_per_eu pinned 2,2; ~210 VGPR, NO spill — W lives in
// named f8 vars w0..w15, every access a compile-time-constant subscript).
// Stage-1: gate g = tid>>6; lane: kg(k-16-group)|no(n-octet)|bg(b-pair).
// Stage-3: thread (b = tid>>6, n = tid&63): gates, c/h, online alpha.
__global__ void __launch_bounds__(256)
    __attribute__((amdgpu_waves_per_eu(2, 2)))
imv_lstm_scan(const float* __restrict__ x,
              const float* __restrict__ Uj, const float* __restrict__ Ui,
              const float* __restrict__ Uf, const float* __restrict__ Uo,
              const float* __restrict__ Wj, const float* __restrict__ Wi,
              const float* __restrict__ Wf, const float* __restrict__ Wo,
              const float* __restrict__ bj, const float* __restrict__ bi_,
              const float* __restrict__ bf_, const float* __restrict__ bo,
              const float* __restrict__ Fa, const float* __restrict__ Fab,
              const float* __restrict__ Fbw, const float* __restrict__ Fbb,
              const float* __restrict__ Pw, const float* __restrict__ Pb,
              float* __restrict__ wmu, float* __restrict__ wbeta)
{
    __shared__ float sX[B_TILE][T_LEN];       // 8 KB
    __shared__ float sH[B_TILE][SH_PAD];      // 1.1 KB
    __shared__ float sG[4][B_TILE][SH_PAD];   // 4.6 KB

    const int tid = threadIdx.x;
    const int d   = blockIdx.x & 31;
    const int bt  = blockIdx.x >> 5;
    const int bg0 = bt * B_TILE;

    // stage-1 role: per gate 64 lanes = kg(2b) | no(3b) | bg(1b)
    const int g   = tid >> 6;
    const int idx = tid & 63;
    const int kg  = idx & 3;
    const int no  = (idx >> 2) & 7;
    const int bg  = idx >> 5;          // 0..1 -> b = bg*2 + bi
    const int n0  = no * 8;
    const int k0  = kg * 16;
    // stage-3 role
    const int b3 = tid >> 6;           // 0..3 (one wave per b)
    const int n3 = tid & 63;

    const float* Wsel = (g == 0) ? Wj : (g == 1) ? Wi : (g == 2) ? Wf : Wo;
    const float* Usel = (g == 0) ? Uj : (g == 1) ? Ui : (g == 2) ? Uf : Uo;
    const float* Bsel = (g == 0) ? bj : (g == 1) ? bi_ : (g == 2) ? bf_ : bo;

    // ---- W slice in NAMED registers: w0..w15 = W[d][k0+K][n0..n0+7] ----
    const float* Wg = Wsel + d * (N_DIM * N_DIM) + n0;
    f8 w0,w1,w2,w3,w4,w5,w6,w7,w8,w9,w10,w11,w12,w13,w14,w15;
#define WLOAD(K) w##K = *(const f8*)(Wg + (k0 + K) * N_DIM);
    WLOAD(0) WLOAD(1) WLOAD(2)  WLOAD(3)  WLOAD(4)  WLOAD(5)  WLOAD(6)  WLOAD(7)
    WLOAD(8) WLOAD(9) WLOAD(10) WLOAD(11) WLOAD(12) WLOAD(13) WLOAD(14) WLOAD(15)
#undef WLOAD

    f8 uv = *(const f8*)(Usel + d * N_DIM + n0);
    f8 bv = *(const f8*)(Bsel + d * N_DIM + n0);
    // x*U + b must be counted once across the 4 kg lanes -> zero others
    const float seed = (kg == 0) ? 1.0f : 0.0f;
    uv = uv * seed;
    bv = bv * seed;

    const float far = Fa[d * N_DIM + n3];
    const float fab = Fab[d];

    // stage x[b, :, d] into LDS (one-time)
    for (int i = tid; i < B_TILE * T_LEN; i += 256) {
        int b = i >> 9, tt = i & (T_LEN - 1);
        sX[b][tt] = x[((size_t)(bg0 + b) * T_LEN + tt) * D_DIM + d];
    }
    for (int i = tid; i < B_TILE * SH_PAD; i += 256)
        ((float*)sH)[i] = 0.f;
    __syncthreads();

    float cst  = 0.f, hst = 0.f;
    float gacc = 0.f, asum = 0.f;

    const int   bi_s = kg >> 1;       // which b of the pair this lane stores
    const int   half = kg & 1;        // which n-quad half this lane stores
    const int   brow0 = bg * 2;

    #pragma unroll 1
    for (int t = 0; t < T_LEN; ++t) {
        // ---------- stage 1: gate matmul (W in regs, h from LDS) ----------
        float xv0 = sX[brow0 + 0][t];
        float xv1 = sX[brow0 + 1][t];
        f8 acc0 = xv0 * uv + bv;
        f8 acc1 = xv1 * uv + bv;

        const float* h0 = &sH[brow0 + 0][k0];
        const float* h1 = &sH[brow0 + 1][k0];
        f8 ha0 = ldsf8(h0);
        f8 ha1 = ldsf8(h1);
        f8 hb0 = ldsf8(h0 + 8);
        f8 hb1 = ldsf8(h1 + 8);

#define KS(K, HA, HB) acc0 += HA[(K) & 7] * w##K; acc1 += HB[(K) & 7] * w##K;
        KS(0,ha0,ha1) KS(1,ha0,ha1) KS(2,ha0,ha1) KS(3,ha0,ha1)
        KS(4,ha0,ha1) KS(5,ha0,ha1) KS(6,ha0,ha1) KS(7,ha0,ha1)
        KS(8,hb0,hb1) KS(9,hb0,hb1) KS(10,hb0,hb1) KS(11,hb0,hb1)
        KS(12,hb0,hb1) KS(13,hb0,hb1) KS(14,hb0,hb1) KS(15,hb0,hb1)
#undef KS

        // combine k-partials across the 4 kg lanes (lane bits 0-1)
#define CMB(I) { float v0 = acc0[I]; v0 += __shfl_xor(v0, 1); v0 += __shfl_xor(v0, 2); acc0[I] = v0; \
                 float v1 = acc1[I]; v1 += __shfl_xor(v1, 1); v1 += __shfl_xor(v1, 2); acc1[I] = v1; }
        CMB(0) CMB(1) CMB(2) CMB(3) CMB(4) CMB(5) CMB(6) CMB(7)
#undef CMB

        // lane kg stores its quarter: b = brow0+bi_s, cols n0+half*4 ..+3
        {
            float e0 = bi_s ? acc1[0] : acc0[0];
            float e1 = bi_s ? acc1[1] : acc0[1];
            float e2 = bi_s ? acc1[2] : acc0[2];
            float e3 = bi_s ? acc1[3] : acc0[3];
            float e4 = bi_s ? acc1[4] : acc0[4];
            float e5 = bi_s ? acc1[5] : acc0[5];
            float e6 = bi_s ? acc1[6] : acc0[6];
            float e7 = bi_s ? acc1[7] : acc0[7];
            float q0 = half ? e4 : e0;
            float q1 = half ? e5 : e1;
            float q2 = half ? e6 : e2;
            float q3 = half ? e7 : e3;
            *(float4*)&sG[g][brow0 + bi_s][n0 + half * 4] =
                make_float4(q0, q1, q2, q3);
        }
        __syncthreads();

        // ---------- stage 3: nonlinearities, state, online alpha ----------
        float jp = sG[0][b3][n3];
        float ip = sG[1][b3][n3];
        float fp = sG[2][b3][n3];
        float op = sG[3][b3][n3];
        float jt = tanh_f(jp);
        float it = sig_f(ip);
        float ft = sig_f(fp);
        float ot = sig_f(op);
        cst = fmaf(cst, ft, it * jt);
        hst = ot * tanh_f(cst);

        float ps = hst * far;
        #pragma unroll
        for (int m = 1; m < 64; m <<= 1)
            ps += __shfl_xor(ps, m);
        float al = __expf(tanh_f(ps + fab));
        asum += al;
        gacc = fmaf(al, hst, gacc);

        sH[b3][n3] = hst;
        __syncthreads();
    }

    // ---------- epilogue: per (b3, d) mu and beta ----------
    float gn  = gacc * (1.0f / asum);
    float pm  = fmaf(gn, Pw[n3],  hst * Pw[64 + n3]);
    float pbv = fmaf(gn, Fbw[n3], hst * Fbw[64 + n3]);
    #pragma unroll
    for (int m = 1; m < 64; m <<= 1) {
        pm  += __shfl_xor(pm, m);
        pbv += __shfl_xor(pbv, m);
    }
    if (n3 == 0) {
        int bglob = bg0 + b3;
        wmu[bglob * D_DIM + d]   = pm + Pb[0];
        wbeta[bglob * D_DIM + d] = __expf(tanh_f(pbv + Fbb[0]));
    }
}

// beta softmax over d + weighted sum -> out[b]
__global__ void imv_finalize(const float* __restrict__ wmu,
                             const float* __restrict__ wbeta,
                             float* __restrict__ out)
{
    int b = blockIdx.x * 64 + threadIdx.x;
    if (b >= B_ALL) return;
    float s1 = 0.f, s2 = 0.f;
    for (int d = 0; d < D_DIM; ++d) {
        float be = wbeta[b * D_DIM + d];
        s1 = fmaf(be, wmu[b * D_DIM + d], s1);
        s2 += be;
    }
    out[b] = s1 / s2;
}

extern "C" void kernel_launch(void* const* d_in, const int* in_sizes, int n_in,
                              void* d_out, int out_size, void* d_ws, size_t ws_size,
                              hipStream_t stream)
{
    const float* x   = (const float*)d_in[0];
    const float* U_j = (const float*)d_in[1];
    const float* U_i = (const float*)d_in[2];
    const float* U_f = (const float*)d_in[3];
    const float* U_o = (const float*)d_in[4];
    const float* W_j = (const float*)d_in[5];
    const float* W_i = (const float*)d_in[6];
    const float* W_f = (const float*)d_in[7];
    const float* W_o = (const float*)d_in[8];
    const float* b_j = (const float*)d_in[9];
    const float* b_i = (const float*)d_in[10];
    const float* b_f = (const float*)d_in[11];
    const float* b_o = (const float*)d_in[12];
    const float* Fan  = (const float*)d_in[13];
    const float* Fanb = (const float*)d_in[14];
    const float* Fbw  = (const float*)d_in[15];
    const float* Fbb  = (const float*)d_in[16];
    const float* Phw  = (const float*)d_in[17];
    const float* Phb  = (const float*)d_in[18];

    float* wmu   = (float*)d_ws;
    float* wbeta = wmu + B_ALL * D_DIM;

    imv_lstm_scan<<<dim3(1024), dim3(256), 0, stream>>>(
        x, U_j, U_i, U_f, U_o, W_j, W_i, W_f, W_o,
        b_j, b_i, b_f, b_o, Fan, Fanb, Fbw, Fbb, Phw, Phb,
        wmu, wbeta);

    imv_finalize<<<dim3(2), dim3(64), 0, stream>>>(wmu, wbeta, (float*)d_out);
}